// Round 2
// baseline (549.646 us; speedup 1.0000x reference)
//
#include <hip/hip_runtime.h>
#include <hip/hip_bf16.h>
#include <math.h>

typedef __hip_bfloat16 bf16;
typedef __bf16  bf16x8  __attribute__((ext_vector_type(8)));
typedef float   floatx4 __attribute__((ext_vector_type(4)));

typedef const __attribute__((address_space(1))) void global_cv_t;
typedef __attribute__((address_space(3))) void       lds_v_t;

static __device__ __forceinline__ float bf2f(bf16 h) { return __bfloat162float(h); }
static __device__ __forceinline__ bf16  f2bf(float f) { return __float2bfloat16(f); }

__device__ __forceinline__ void load_lds16(const void* g, void* l) {
    // async global->LDS, 16B per lane; LDS dest = wave-uniform base + lane*16
    __builtin_amdgcn_global_load_lds((global_cv_t*)g, (lds_v_t*)l, 16, 0, 0);
}

// ---------------------------------------------------------------------------
// x (f32, 16M elems) -> bf16, vectorized
// ---------------------------------------------------------------------------
__global__ __launch_bounds__(256) void convx_k(const float4* __restrict__ in,
                                               bf16* __restrict__ out)
{
    const int i = blockIdx.x * 256 + threadIdx.x;   // 0 .. 4194303
    const float4 v = in[i];
    bf16* o = out + (size_t)i * 4;
    o[0] = f2bf(v.x); o[1] = f2bf(v.y); o[2] = f2bf(v.z); o[3] = f2bf(v.w);
}

// ---------------------------------------------------------------------------
// Transpose+convert 5x (1024x1024 f32): dst[n][k] = (bf16)src[k][n]
// ---------------------------------------------------------------------------
__global__ __launch_bounds__(256) void trc_k(
    const float* __restrict__ w0, const float* __restrict__ w1,
    const float* __restrict__ w2, const float* __restrict__ w3,
    const float* __restrict__ w4, bf16* __restrict__ dst)
{
    const float* src;
    switch (blockIdx.z) {
        case 0: src = w0; break;
        case 1: src = w1; break;
        case 2: src = w2; break;
        case 3: src = w3; break;
        default: src = w4; break;
    }
    bf16* d = dst + ((size_t)blockIdx.z << 20);
    __shared__ float tile[32][33];
    const int tx = threadIdx.x & 31;
    const int ty = threadIdx.x >> 5;   // 0..7
    const int bx = blockIdx.x * 32, by = blockIdx.y * 32;
#pragma unroll
    for (int j = 0; j < 32; j += 8)
        tile[ty + j][tx] = src[(size_t)(by + ty + j) * 1024 + bx + tx];
    __syncthreads();
#pragma unroll
    for (int j = 0; j < 32; j += 8)
        d[(size_t)(bx + ty + j) * 1024 + by + tx] = f2bf(tile[tx][ty + j]);
}

// ---------------------------------------------------------------------------
// GEMM: C[m][n] = sum_k A[m][k] * Bt[n][k] + bias[n], mode-dependent epilogue.
// A, Bt bf16; bias f32. M=16384, N=1024, K=1024. 128x128 tile, BK=32, 4 waves.
// modes: 0=tanh->Db  1=sigmoid*(1-auxf[row])->Db  2=plain->Db  3=gelu->Db
//        4=(+auxb residual)->Df (f32)
// ---------------------------------------------------------------------------
__global__ __launch_bounds__(256) void gemm_k(
    const bf16* __restrict__ A, const bf16* __restrict__ Bt,
    const float* __restrict__ bias, const float* __restrict__ auxf,
    const bf16* __restrict__ auxb, bf16* __restrict__ Db,
    float* __restrict__ Df, const int mode)
{
    __shared__ alignas(16) bf16 As[128 * 32];   // [m][k], k contiguous (no pad: global_load_lds)
    __shared__ alignas(16) bf16 Bs[128 * 32];   // [n][k]

    const int tid  = threadIdx.x;
    const int wave = tid >> 6;
    const int lane = tid & 63;
    const int quad = lane >> 4;
    const int l16  = lane & 15;
    const int wm   = wave & 1;      // wave row (64 rows)
    const int wn   = wave >> 1;     // wave col (64 cols)
    const int bm   = blockIdx.x * 128;
    const int bn   = blockIdx.y * 128;

    // staging: each wave fills two 1KB LDS chunks per matrix per K-iter.
    const int srow  = lane >> 2;
    const int skoff = (lane & 3) << 3;
    const int c0 = wave * 2, c1 = wave * 2 + 1;

    const bf16* gA0 = A  + (size_t)(bm + c0 * 16 + srow) * 1024 + skoff;
    const bf16* gA1 = A  + (size_t)(bm + c1 * 16 + srow) * 1024 + skoff;
    const bf16* gB0 = Bt + (size_t)(bn + c0 * 16 + srow) * 1024 + skoff;
    const bf16* gB1 = Bt + (size_t)(bn + c1 * 16 + srow) * 1024 + skoff;

    floatx4 acc[4][4];
#pragma unroll
    for (int i = 0; i < 4; ++i)
#pragma unroll
        for (int j = 0; j < 4; ++j)
            acc[i][j] = (floatx4){0.f, 0.f, 0.f, 0.f};

    for (int k0 = 0; k0 < 1024; k0 += 32) {
        __syncthreads();
        load_lds16(gA0 + k0, &As[c0 * 512]);
        load_lds16(gA1 + k0, &As[c1 * 512]);
        load_lds16(gB0 + k0, &Bs[c0 * 512]);
        load_lds16(gB1 + k0, &Bs[c1 * 512]);
        __syncthreads();   // compiler emits s_waitcnt vmcnt(0) before s_barrier

        bf16x8 af[4], bfr[4];
#pragma unroll
        for (int t = 0; t < 4; ++t) {
            af[t]  = *(const bf16x8*)&As[(wm * 64 + t * 16 + l16) * 32 + quad * 8];
            bfr[t] = *(const bf16x8*)&Bs[(wn * 64 + t * 16 + l16) * 32 + quad * 8];
        }
#pragma unroll
        for (int tm = 0; tm < 4; ++tm)
#pragma unroll
            for (int tn = 0; tn < 4; ++tn)
                acc[tm][tn] = __builtin_amdgcn_mfma_f32_16x16x32_bf16(
                    af[tm], bfr[tn], acc[tm][tn], 0, 0, 0);
    }

    // epilogue. C/D layout: col = lane&15, row = quad*4 + reg (m89-verified)
    float bv[4];
#pragma unroll
    for (int tn = 0; tn < 4; ++tn)
        bv[tn] = bias[bn + wn * 64 + tn * 16 + l16];

#pragma unroll
    for (int tm = 0; tm < 4; ++tm) {
#pragma unroll
        for (int r = 0; r < 4; ++r) {
            const int gm = bm + wm * 64 + tm * 16 + quad * 4 + r;
            const size_t rowoff = (size_t)gm << 10;
            float rowmul = 1.f;
            if (mode == 1) rowmul = 1.f - auxf[gm];
#pragma unroll
            for (int tn = 0; tn < 4; ++tn) {
                const int gn = bn + wn * 64 + tn * 16 + l16;
                float val = acc[tm][tn][r] + bv[tn];
                if (mode == 0)      val = tanhf(val);
                else if (mode == 1) val = rowmul / (1.f + expf(-val));
                else if (mode == 3) val = 0.5f * val * (1.f + erff(val * 0.70710678118654752f));
                if (mode == 4) {
                    val += bf2f(auxb[rowoff + gn]);
                    Df[rowoff + gn] = val;
                } else {
                    Db[rowoff + gn] = f2bf(val);
                }
            }
        }
    }
}

// ---------------------------------------------------------------------------
// Chunked linear-recurrence scan: h[t] = f[t]*h[t-1] + (1-f[t])*v[t].
// T=4096 split into 64 chunks of 64. 4096 channels (b,d).
// pass1: per-chunk composite  h_end = Ac*h_in + Bc   (Ac = prod f, Bc = local scan from 0)
// mid:   propagate h_in across chunks (sequential over 64, parallel over channels)
// pass2: recompute local scan from correct h_in; write hs (bf16) and hT (f32)
// ---------------------------------------------------------------------------
__global__ __launch_bounds__(256) void scan1_k(
    const bf16* __restrict__ v, const bf16* __restrict__ f,
    float* __restrict__ Ac, float* __restrict__ Bc)
{
    const int idx = blockIdx.x * 256 + threadIdx.x;   // 0..262143
    const int ch = idx & 4095;        // b*1024 + d
    const int c  = idx >> 12;         // chunk 0..63
    const int b  = ch >> 10, d = ch & 1023;
    const size_t base = ((size_t)(b * 4096 + c * 64) << 10) + d;
    float a = 1.f, hb = 0.f;
#pragma unroll 8
    for (int i = 0; i < 64; ++i) {
        const size_t o = base + ((size_t)i << 10);
        const float ft = bf2f(f[o]);
        const float vt = bf2f(v[o]);
        hb = fmaf(ft, hb, (1.f - ft) * vt);
        a *= ft;
    }
    Ac[c * 4096 + ch] = a;
    Bc[c * 4096 + ch] = hb;
}

__global__ __launch_bounds__(256) void scanmid_k(
    const float* __restrict__ Ac, const float* __restrict__ Bc,
    const float* __restrict__ hidden, float* __restrict__ Hin)
{
    const int ch = blockIdx.x * 256 + threadIdx.x;    // 0..4095
    float h = hidden[ch];                             // hidden (4,1,1024) flat
#pragma unroll 8
    for (int c = 0; c < 64; ++c) {
        Hin[c * 4096 + ch] = h;
        h = fmaf(Ac[c * 4096 + ch], h, Bc[c * 4096 + ch]);
    }
}

__global__ __launch_bounds__(256) void scan2_k(
    const bf16* __restrict__ v, const bf16* __restrict__ f,
    const float* __restrict__ Hin, bf16* __restrict__ hs,
    float* __restrict__ hT)
{
    const int idx = blockIdx.x * 256 + threadIdx.x;
    const int ch = idx & 4095;
    const int c  = idx >> 12;
    const int b  = ch >> 10, d = ch & 1023;
    const size_t base = ((size_t)(b * 4096 + c * 64) << 10) + d;
    float h = Hin[c * 4096 + ch];
#pragma unroll 8
    for (int i = 0; i < 64; ++i) {
        const size_t o = base + ((size_t)i << 10);
        const float ft = bf2f(f[o]);
        const float vt = bf2f(v[o]);
        h = fmaf(ft, h, (1.f - ft) * vt);
        hs[o] = f2bf(h);
    }
    if (c == 63) hT[ch] = h;
}

// ---------------------------------------------------------------------------
// LayerNorm over D=1024 (f32 in-place on d_out), one block per row.
// ---------------------------------------------------------------------------
__global__ __launch_bounds__(256) void ln_k(
    float* __restrict__ s, const float* __restrict__ g,
    const float* __restrict__ b)
{
    const int row = blockIdx.x;
    const int tid = threadIdx.x;
    const size_t off = (size_t)row << 10;
    const float4 xv = ((const float4*)(s + off))[tid];
    float sum = xv.x + xv.y + xv.z + xv.w;
    float sq  = xv.x * xv.x + xv.y * xv.y + xv.z * xv.z + xv.w * xv.w;
#pragma unroll
    for (int o = 32; o > 0; o >>= 1) {
        sum += __shfl_down(sum, o, 64);
        sq  += __shfl_down(sq,  o, 64);
    }
    __shared__ float s1[4], s2[4];
    if ((tid & 63) == 0) { s1[tid >> 6] = sum; s2[tid >> 6] = sq; }
    __syncthreads();
    sum = s1[0] + s1[1] + s1[2] + s1[3];
    sq  = s2[0] + s2[1] + s2[2] + s2[3];
    const float mean = sum * (1.f / 1024.f);
    const float var  = sq * (1.f / 1024.f) - mean * mean;
    const float rstd = rsqrtf(var + 1e-5f);
    const float4 gv = ((const float4*)g)[tid];
    const float4 bv = ((const float4*)b)[tid];
    float4 y;
    y.x = (xv.x - mean) * rstd * gv.x + bv.x;
    y.y = (xv.y - mean) * rstd * gv.y + bv.y;
    y.z = (xv.z - mean) * rstd * gv.z + bv.z;
    y.w = (xv.w - mean) * rstd * gv.w + bv.w;
    ((float4*)(s + off))[tid] = y;
}

// ---------------------------------------------------------------------------
extern "C" void kernel_launch(void* const* d_in, const int* in_sizes, int n_in,
                              void* d_out, int out_size, void* d_ws, size_t ws_size,
                              hipStream_t stream)
{
    const float* x         = (const float*)d_in[0];   // (4,4096,1024)
    const float* hidden    = (const float*)d_in[1];   // (4,1,1024)
    const float* rnn_start = (const float*)d_in[2];   // (4,4096,1)
    const float* Win       = (const float*)d_in[3];   // (2,1024,1024)
    const float* bin_      = (const float*)d_in[4];   // (2,1024)
    const float* Wout      = (const float*)d_in[5];   // (1024,1024)
    const float* bout      = (const float*)d_in[6];
    const float* W1        = (const float*)d_in[7];
    const float* b1        = (const float*)d_in[8];
    const float* W2        = (const float*)d_in[9];
    const float* b2        = (const float*)d_in[10];
    const float* ln_g      = (const float*)d_in[11];
    const float* ln_b      = (const float*)d_in[12];
    float* out = (float*)d_out;                // out(16777216 f32) ++ hidden_new(4096 f32)
    float* hT  = out + (1u << 24);

    // workspace layout
    char* p = (char*)d_ws;
    bf16* Wt   = (bf16*)p;                     p += 5ull * (1u << 20) * sizeof(bf16);  // 5 transposed bf16 weights
    bf16* slotA = (bf16*)p;                    p += (1ull << 24) * sizeof(bf16);  // xb, later hs
    bf16* slotB = (bf16*)p;                    p += (1ull << 24) * sizeof(bf16);  // v,  later outp
    bf16* slotC = (bf16*)p;                    p += (1ull << 24) * sizeof(bf16);  // f,  later x_
    float* Ac  = (float*)p;                    p += (1ull << 18) * sizeof(float);
    float* Bc  = (float*)p;                    p += (1ull << 18) * sizeof(float);
    float* Hin = (float*)p;                    p += (1ull << 18) * sizeof(float);

    bf16* WinT0 = Wt;
    bf16* WinT1 = Wt + (1u << 20);
    bf16* WoutT = Wt + 2u * (1u << 20);
    bf16* W1T   = Wt + 3u * (1u << 20);
    bf16* W2T   = Wt + 4u * (1u << 20);

    convx_k<<<16384, 256, 0, stream>>>((const float4*)x, slotA);
    trc_k<<<dim3(32, 32, 5), 256, 0, stream>>>(Win, Win + (1u << 20), Wout, W1, W2, Wt);

    // u0 -> v = tanh(u0), u1 -> f = sigmoid(u1)*(1-rnn_start)
    gemm_k<<<dim3(128, 8), 256, 0, stream>>>(slotA, WinT0, bin_,        nullptr,   nullptr, slotB, nullptr, 0);
    gemm_k<<<dim3(128, 8), 256, 0, stream>>>(slotA, WinT1, bin_ + 1024, rnn_start, nullptr, slotC, nullptr, 1);

    // chunked scan: v=slotB, f=slotC -> hs=slotA (xb dead), hT -> d_out tail
    scan1_k<<<1024, 256, 0, stream>>>(slotB, slotC, Ac, Bc);
    scanmid_k<<<16, 256, 0, stream>>>(Ac, Bc, hidden, Hin);
    scan2_k<<<1024, 256, 0, stream>>>(slotB, slotC, Hin, slotA, hT);

    // outp = hs@Wout + bout (-> slotB); x_ = gelu(outp@W1+b1) (-> slotC);
    // s = x_@W2 + b2 + outp  -> f32 in d_out
    gemm_k<<<dim3(128, 8), 256, 0, stream>>>(slotA, WoutT, bout, nullptr, nullptr, slotB, nullptr, 2);
    gemm_k<<<dim3(128, 8), 256, 0, stream>>>(slotB, W1T,   b1,   nullptr, nullptr, slotC, nullptr, 3);
    gemm_k<<<dim3(128, 8), 256, 0, stream>>>(slotC, W2T,   b2,   nullptr, slotB,   nullptr, out, 4);

    ln_k<<<16384, 256, 0, stream>>>(out, ln_g, ln_b);
}

// Round 3
// 440.421 us; speedup vs baseline: 1.2480x; 1.2480x over previous
//
#include <hip/hip_runtime.h>
#include <hip/hip_bf16.h>
#include <math.h>

typedef __hip_bfloat16 bf16;
typedef __bf16  bf16x8  __attribute__((ext_vector_type(8)));
typedef float   floatx4 __attribute__((ext_vector_type(4)));

typedef const __attribute__((address_space(1))) void global_cv_t;
typedef __attribute__((address_space(3))) void       lds_v_t;

static __device__ __forceinline__ float bf2f(bf16 h) { return __bfloat162float(h); }
static __device__ __forceinline__ bf16  f2bf(float f) { return __float2bfloat16(f); }

__device__ __forceinline__ void load_lds16(const void* g, void* l) {
    // async global->LDS, 16B per lane; LDS dest = wave-uniform base + lane*16
    __builtin_amdgcn_global_load_lds((global_cv_t*)g, (lds_v_t*)l, 16, 0, 0);
}

// ---------------------------------------------------------------------------
// x (f32, 16M elems) -> bf16, vectorized
// ---------------------------------------------------------------------------
__global__ __launch_bounds__(256) void convx_k(const float4* __restrict__ in,
                                               bf16* __restrict__ out)
{
    const int i = blockIdx.x * 256 + threadIdx.x;   // 0 .. 4194303
    const float4 v = in[i];
    bf16* o = out + (size_t)i * 4;
    o[0] = f2bf(v.x); o[1] = f2bf(v.y); o[2] = f2bf(v.z); o[3] = f2bf(v.w);
}

// ---------------------------------------------------------------------------
// Transpose+convert 5x (1024x1024 f32): dst[n][k] = (bf16)src[k][n]
// ---------------------------------------------------------------------------
__global__ __launch_bounds__(256) void trc_k(
    const float* __restrict__ w0, const float* __restrict__ w1,
    const float* __restrict__ w2, const float* __restrict__ w3,
    const float* __restrict__ w4, bf16* __restrict__ dst)
{
    const float* src;
    switch (blockIdx.z) {
        case 0: src = w0; break;
        case 1: src = w1; break;
        case 2: src = w2; break;
        case 3: src = w3; break;
        default: src = w4; break;
    }
    bf16* d = dst + ((size_t)blockIdx.z << 20);
    __shared__ float tile[32][33];
    const int tx = threadIdx.x & 31;
    const int ty = threadIdx.x >> 5;   // 0..7
    const int bx = blockIdx.x * 32, by = blockIdx.y * 32;
#pragma unroll
    for (int j = 0; j < 32; j += 8)
        tile[ty + j][tx] = src[(size_t)(by + ty + j) * 1024 + bx + tx];
    __syncthreads();
#pragma unroll
    for (int j = 0; j < 32; j += 8)
        d[(size_t)(bx + ty + j) * 1024 + by + tx] = f2bf(tile[tx][ty + j]);
}

// ---------------------------------------------------------------------------
// GEMM: C[m][n] = sum_k A[m][k] * Bt[n][k] + bias[n], mode-dependent epilogue.
// A, Bt bf16; bias f32. M=16384, N=1024, K=1024. 128x128 tile, BK=64, 4 waves.
// BK=64: 16 K-iters (half the barrier-drain latency events of BK=32), 32 KB
// LDS/block -> still 4 blocks/CU resident (grid-capped).
// modes: 0=tanh->Db  1=sigmoid*(1-auxf[row])->Db  2=plain->Db  3=gelu->Db
//        4=(+auxb residual)->Df (f32)
//        5=dual: blockIdx.y selects {WinT0->tanh->Db, WinT1->sigmoid->Db2}
// ---------------------------------------------------------------------------
__global__ __launch_bounds__(256, 4) void gemm_k(
    const bf16* __restrict__ A, const bf16* __restrict__ Bt,
    const float* __restrict__ bias, const float* __restrict__ auxf,
    const bf16* __restrict__ auxb, bf16* __restrict__ Db,
    bf16* __restrict__ Db2, float* __restrict__ Df, const int mode)
{
    __shared__ alignas(16) bf16 As[128 * 64];   // [m][k], k contiguous (no pad: global_load_lds)
    __shared__ alignas(16) bf16 Bs[128 * 64];   // [n][k]

    const int tid  = threadIdx.x;
    const int wave = tid >> 6;
    const int lane = tid & 63;
    const int quad = lane >> 4;
    const int l16  = lane & 15;
    const int wm   = wave & 1;      // wave row (64 rows)
    const int wn   = wave >> 1;     // wave col (64 cols)
    const int bm   = blockIdx.x * 128;

    int bn, emode;
    const bf16* Bte = Bt;
    const float* biase = bias;
    bf16* Dbe = Db;
    if (mode == 5) {
        const int mat = blockIdx.y >> 3;          // 0: tanh/Win0, 1: sigmoid/Win1
        bn    = (blockIdx.y & 7) * 128;
        Bte   = Bt + ((size_t)mat << 20);
        biase = bias + (mat << 10);
        Dbe   = mat ? Db2 : Db;
        emode = mat ? 1 : 0;
    } else {
        bn = blockIdx.y * 128;
        emode = mode;
    }

    // staging (BK=64): chunk = 8 rows x 64 k = 1 KB. lane l -> row l>>3, k-off (l&7)*8.
    // per wave: 4 A-chunks + 4 B-chunks per K-iter (8 x 1KB in flight).
    const int srow  = lane >> 3;
    const int skoff = (lane & 7) << 3;

    const bf16* gA = A   + (size_t)(bm + wave * 32 + srow) * 1024 + skoff;
    const bf16* gB = Bte + (size_t)(bn + wave * 32 + srow) * 1024 + skoff;
    bf16* lA = &As[wave * 2048];
    bf16* lB = &Bs[wave * 2048];

    floatx4 acc[4][4];
#pragma unroll
    for (int i = 0; i < 4; ++i)
#pragma unroll
        for (int j = 0; j < 4; ++j)
            acc[i][j] = (floatx4){0.f, 0.f, 0.f, 0.f};

    for (int k0 = 0; k0 < 1024; k0 += 64) {
        __syncthreads();
#pragma unroll
        for (int c = 0; c < 4; ++c) {
            load_lds16(gA + (size_t)c * 8192 + k0, lA + c * 512);
            load_lds16(gB + (size_t)c * 8192 + k0, lB + c * 512);
        }
        __syncthreads();   // vmcnt(0) drain before barrier

#pragma unroll
        for (int kk = 0; kk < 2; ++kk) {
            bf16x8 af[4], bfr[4];
#pragma unroll
            for (int t = 0; t < 4; ++t) {
                af[t]  = *(const bf16x8*)&As[(wm * 64 + t * 16 + l16) * 64 + kk * 32 + quad * 8];
                bfr[t] = *(const bf16x8*)&Bs[(wn * 64 + t * 16 + l16) * 64 + kk * 32 + quad * 8];
            }
#pragma unroll
            for (int tm = 0; tm < 4; ++tm)
#pragma unroll
                for (int tn = 0; tn < 4; ++tn)
                    acc[tm][tn] = __builtin_amdgcn_mfma_f32_16x16x32_bf16(
                        af[tm], bfr[tn], acc[tm][tn], 0, 0, 0);
        }
    }

    // epilogue. C/D layout: col = lane&15, row = quad*4 + reg (m89-verified)
    float bv[4];
#pragma unroll
    for (int tn = 0; tn < 4; ++tn)
        bv[tn] = biase[bn + wn * 64 + tn * 16 + l16];

#pragma unroll
    for (int tm = 0; tm < 4; ++tm) {
#pragma unroll
        for (int r = 0; r < 4; ++r) {
            const int gm = bm + wm * 64 + tm * 16 + quad * 4 + r;
            const size_t rowoff = (size_t)gm << 10;
            float rowmul = 1.f;
            if (emode == 1) rowmul = 1.f - auxf[gm];
#pragma unroll
            for (int tn = 0; tn < 4; ++tn) {
                const int gn = bn + wn * 64 + tn * 16 + l16;
                float val = acc[tm][tn][r] + bv[tn];
                if (emode == 0)      val = tanhf(val);
                else if (emode == 1) val = rowmul / (1.f + expf(-val));
                else if (emode == 3) val = 0.5f * val * (1.f + erff(val * 0.70710678118654752f));
                if (emode == 4) {
                    val += bf2f(auxb[rowoff + gn]);
                    Df[rowoff + gn] = val;
                } else {
                    Dbe[rowoff + gn] = f2bf(val);
                }
            }
        }
    }
}

// ---------------------------------------------------------------------------
// Chunked linear-recurrence scan: h[t] = f[t]*h[t-1] + (1-f[t])*v[t].
// T=4096 split into 64 chunks of 64. 4096 channels (b,d).
// ---------------------------------------------------------------------------
__global__ __launch_bounds__(256) void scan1_k(
    const bf16* __restrict__ v, const bf16* __restrict__ f,
    float* __restrict__ Ac, float* __restrict__ Bc)
{
    const int idx = blockIdx.x * 256 + threadIdx.x;   // 0..262143
    const int ch = idx & 4095;        // b*1024 + d
    const int c  = idx >> 12;         // chunk 0..63
    const int b  = ch >> 10, d = ch & 1023;
    const size_t base = ((size_t)(b * 4096 + c * 64) << 10) + d;
    float a = 1.f, hb = 0.f;
#pragma unroll 8
    for (int i = 0; i < 64; ++i) {
        const size_t o = base + ((size_t)i << 10);
        const float ft = bf2f(f[o]);
        const float vt = bf2f(v[o]);
        hb = fmaf(ft, hb, (1.f - ft) * vt);
        a *= ft;
    }
    Ac[c * 4096 + ch] = a;
    Bc[c * 4096 + ch] = hb;
}

__global__ __launch_bounds__(256) void scanmid_k(
    const float* __restrict__ Ac, const float* __restrict__ Bc,
    const float* __restrict__ hidden, float* __restrict__ Hin)
{
    const int ch = blockIdx.x * 256 + threadIdx.x;    // 0..4095
    float h = hidden[ch];
#pragma unroll 8
    for (int c = 0; c < 64; ++c) {
        Hin[c * 4096 + ch] = h;
        h = fmaf(Ac[c * 4096 + ch], h, Bc[c * 4096 + ch]);
    }
}

__global__ __launch_bounds__(256) void scan2_k(
    const bf16* __restrict__ v, const bf16* __restrict__ f,
    const float* __restrict__ Hin, bf16* __restrict__ hs,
    float* __restrict__ hT)
{
    const int idx = blockIdx.x * 256 + threadIdx.x;
    const int ch = idx & 4095;
    const int c  = idx >> 12;
    const int b  = ch >> 10, d = ch & 1023;
    const size_t base = ((size_t)(b * 4096 + c * 64) << 10) + d;
    float h = Hin[c * 4096 + ch];
#pragma unroll 8
    for (int i = 0; i < 64; ++i) {
        const size_t o = base + ((size_t)i << 10);
        const float ft = bf2f(f[o]);
        const float vt = bf2f(v[o]);
        h = fmaf(ft, h, (1.f - ft) * vt);
        hs[o] = f2bf(h);
    }
    if (c == 63) hT[ch] = h;
}

// ---------------------------------------------------------------------------
// LayerNorm over D=1024 (f32 in-place on d_out), one block per row.
// ---------------------------------------------------------------------------
__global__ __launch_bounds__(256) void ln_k(
    float* __restrict__ s, const float* __restrict__ g,
    const float* __restrict__ b)
{
    const int row = blockIdx.x;
    const int tid = threadIdx.x;
    const size_t off = (size_t)row << 10;
    const float4 xv = ((const float4*)(s + off))[tid];
    float sum = xv.x + xv.y + xv.z + xv.w;
    float sq  = xv.x * xv.x + xv.y * xv.y + xv.z * xv.z + xv.w * xv.w;
#pragma unroll
    for (int o = 32; o > 0; o >>= 1) {
        sum += __shfl_down(sum, o, 64);
        sq  += __shfl_down(sq,  o, 64);
    }
    __shared__ float s1[4], s2[4];
    if ((tid & 63) == 0) { s1[tid >> 6] = sum; s2[tid >> 6] = sq; }
    __syncthreads();
    sum = s1[0] + s1[1] + s1[2] + s1[3];
    sq  = s2[0] + s2[1] + s2[2] + s2[3];
    const float mean = sum * (1.f / 1024.f);
    const float var  = sq * (1.f / 1024.f) - mean * mean;
    const float rstd = rsqrtf(var + 1e-5f);
    const float4 gv = ((const float4*)g)[tid];
    const float4 bv = ((const float4*)b)[tid];
    float4 y;
    y.x = (xv.x - mean) * rstd * gv.x + bv.x;
    y.y = (xv.y - mean) * rstd * gv.y + bv.y;
    y.z = (xv.z - mean) * rstd * gv.z + bv.z;
    y.w = (xv.w - mean) * rstd * gv.w + bv.w;
    ((float4*)(s + off))[tid] = y;
}

// ---------------------------------------------------------------------------
extern "C" void kernel_launch(void* const* d_in, const int* in_sizes, int n_in,
                              void* d_out, int out_size, void* d_ws, size_t ws_size,
                              hipStream_t stream)
{
    const float* x         = (const float*)d_in[0];   // (4,4096,1024)
    const float* hidden    = (const float*)d_in[1];   // (4,1,1024)
    const float* rnn_start = (const float*)d_in[2];   // (4,4096,1)
    const float* Win       = (const float*)d_in[3];   // (2,1024,1024)
    const float* bin_      = (const float*)d_in[4];   // (2,1024)
    const float* Wout      = (const float*)d_in[5];
    const float* bout      = (const float*)d_in[6];
    const float* W1        = (const float*)d_in[7];
    const float* b1        = (const float*)d_in[8];
    const float* W2        = (const float*)d_in[9];
    const float* b2        = (const float*)d_in[10];
    const float* ln_g      = (const float*)d_in[11];
    const float* ln_b      = (const float*)d_in[12];
    float* out = (float*)d_out;                // out(16777216 f32) ++ hidden_new(4096 f32)
    float* hT  = out + (1u << 24);

    // workspace layout
    char* p = (char*)d_ws;
    bf16* Wt    = (bf16*)p;                    p += 5ull * (1u << 20) * sizeof(bf16);
    bf16* slotA = (bf16*)p;                    p += (1ull << 24) * sizeof(bf16);  // xb, later hs
    bf16* slotB = (bf16*)p;                    p += (1ull << 24) * sizeof(bf16);  // v,  later outp
    bf16* slotC = (bf16*)p;                    p += (1ull << 24) * sizeof(bf16);  // f,  later x_
    float* Ac  = (float*)p;                    p += (1ull << 18) * sizeof(float);
    float* Bc  = (float*)p;                    p += (1ull << 18) * sizeof(float);
    float* Hin = (float*)p;                    p += (1ull << 18) * sizeof(float);

    bf16* WoutT = Wt + 2u * (1u << 20);
    bf16* W1T   = Wt + 3u * (1u << 20);
    bf16* W2T   = Wt + 4u * (1u << 20);

    convx_k<<<16384, 256, 0, stream>>>((const float4*)x, slotA);
    trc_k<<<dim3(32, 32, 5), 256, 0, stream>>>(Win, Win + (1u << 20), Wout, W1, W2, Wt);

    // merged dual GEMM: y>=8 -> Win1/sigmoid.  v -> slotB, f -> slotC
    gemm_k<<<dim3(128, 16), 256, 0, stream>>>(slotA, Wt, bin_, rnn_start, nullptr,
                                              slotB, slotC, nullptr, 5);

    // chunked scan: hs -> slotA (xb dead), hT -> d_out tail
    scan1_k<<<1024, 256, 0, stream>>>(slotB, slotC, Ac, Bc);
    scanmid_k<<<16, 256, 0, stream>>>(Ac, Bc, hidden, Hin);
    scan2_k<<<1024, 256, 0, stream>>>(slotB, slotC, Hin, slotA, hT);

    // outp = hs@Wout + bout (-> slotB); x_ = gelu(outp@W1+b1) (-> slotC);
    // s = x_@W2 + b2 + outp -> f32 in d_out
    gemm_k<<<dim3(128, 8), 256, 0, stream>>>(slotA, WoutT, bout, nullptr, nullptr,
                                             slotB, nullptr, nullptr, 2);
    gemm_k<<<dim3(128, 8), 256, 0, stream>>>(slotB, W1T,   b1,   nullptr, nullptr,
                                             slotC, nullptr, nullptr, 3);
    gemm_k<<<dim3(128, 8), 256, 0, stream>>>(slotC, W2T,   b2,   nullptr, slotB,
                                             nullptr, nullptr, out, 4);

    ln_k<<<16384, 256, 0, stream>>>(out, ln_g, ln_b);
}

// Round 4
// 418.026 us; speedup vs baseline: 1.3149x; 1.0536x over previous
//
#include <hip/hip_runtime.h>
#include <hip/hip_bf16.h>
#include <math.h>

typedef __hip_bfloat16 bf16;
typedef __bf16  bf16x8  __attribute__((ext_vector_type(8)));
typedef float   floatx4 __attribute__((ext_vector_type(4)));

typedef const __attribute__((address_space(1))) void global_cv_t;
typedef __attribute__((address_space(3))) void       lds_v_t;

static __device__ __forceinline__ float bf2f(bf16 h) { return __bfloat162float(h); }
static __device__ __forceinline__ bf16  f2bf(float f) { return __float2bfloat16(f); }

__device__ __forceinline__ void load_lds16(const void* g, void* l) {
    // async global->LDS, 16B per lane; LDS dest = wave-uniform base + lane*16
    __builtin_amdgcn_global_load_lds((global_cv_t*)g, (lds_v_t*)l, 16, 0, 0);
}

// ---------------------------------------------------------------------------
// x (f32, 16M elems) -> bf16, vectorized
// ---------------------------------------------------------------------------
__global__ __launch_bounds__(256) void convx_k(const float4* __restrict__ in,
                                               bf16* __restrict__ out)
{
    const int i = blockIdx.x * 256 + threadIdx.x;   // 0 .. 4194303
    const float4 v = in[i];
    bf16* o = out + (size_t)i * 4;
    o[0] = f2bf(v.x); o[1] = f2bf(v.y); o[2] = f2bf(v.z); o[3] = f2bf(v.w);
}

// ---------------------------------------------------------------------------
// Transpose+convert 5x (1024x1024 f32): dst[n][k] = (bf16)src[k][n]
// ---------------------------------------------------------------------------
__global__ __launch_bounds__(256) void trc_k(
    const float* __restrict__ w0, const float* __restrict__ w1,
    const float* __restrict__ w2, const float* __restrict__ w3,
    const float* __restrict__ w4, bf16* __restrict__ dst)
{
    const float* src;
    switch (blockIdx.z) {
        case 0: src = w0; break;
        case 1: src = w1; break;
        case 2: src = w2; break;
        case 3: src = w3; break;
        default: src = w4; break;
    }
    bf16* d = dst + ((size_t)blockIdx.z << 20);
    __shared__ float tile[32][33];
    const int tx = threadIdx.x & 31;
    const int ty = threadIdx.x >> 5;   // 0..7
    const int bx = blockIdx.x * 32, by = blockIdx.y * 32;
#pragma unroll
    for (int j = 0; j < 32; j += 8)
        tile[ty + j][tx] = src[(size_t)(by + ty + j) * 1024 + bx + tx];
    __syncthreads();
#pragma unroll
    for (int j = 0; j < 32; j += 8)
        d[(size_t)(bx + ty + j) * 1024 + by + tx] = f2bf(tile[tx][ty + j]);
}

// ---------------------------------------------------------------------------
// GEMM: C[m][n] = sum_k A[m][k] * Bt[n][k] + bias[n], mode-dependent epilogue.
// A, Bt bf16; bias f32. M=16384, N=1024, K=1024. 128x128 tile, BK=64, 4 waves.
// LDS layout is XOR-swizzled on the 16B k-granule: row r, granule g lives at
// LDS granule (g ^ (r&7)). Staging permutes the per-lane GLOBAL address (free,
// same 128B segment), so global_load_lds's fixed lane->base+lane*16 mapping
// yields the swizzled layout; fragment ds_read_b128 then spreads 64 lanes
// uniformly over all 32 banks (8 words/bank = the hw minimum).
// modes: 0=tanh->Db  1=sigmoid*(1-auxf[row])->Db  2=plain->Db  3=gelu->Db
//        4=(+auxb residual)->Df (f32)
//        5=dual: blockIdx.y selects {WinT0->tanh->Db, WinT1->sigmoid->Db2}
// ---------------------------------------------------------------------------
__global__ __launch_bounds__(256, 4) void gemm_k(
    const bf16* __restrict__ A, const bf16* __restrict__ Bt,
    const float* __restrict__ bias, const float* __restrict__ auxf,
    const bf16* __restrict__ auxb, bf16* __restrict__ Db,
    bf16* __restrict__ Db2, float* __restrict__ Df, const int mode)
{
    __shared__ alignas(16) bf16 As[128 * 64];
    __shared__ alignas(16) bf16 Bs[128 * 64];

    const int tid  = threadIdx.x;
    const int wave = tid >> 6;
    const int lane = tid & 63;
    const int quad = lane >> 4;
    const int l16  = lane & 15;
    const int sw   = l16 & 7;       // row-derived XOR key for fragment reads
    const int wm   = wave & 1;      // wave row (64 rows)
    const int wn   = wave >> 1;     // wave col (64 cols)
    const int bm   = blockIdx.x * 128;

    int bn, emode;
    const bf16* Bte = Bt;
    const float* biase = bias;
    bf16* Dbe = Db;
    if (mode == 5) {
        const int mat = blockIdx.y >> 3;          // 0: tanh/Win0, 1: sigmoid/Win1
        bn    = (blockIdx.y & 7) * 128;
        Bte   = Bt + ((size_t)mat << 20);
        biase = bias + (mat << 10);
        Dbe   = mat ? Db2 : Db;
        emode = mat ? 1 : 0;
    } else {
        bn = blockIdx.y * 128;
        emode = mode;
    }

    // staging (BK=64): chunk = 8 rows x 64 k = 1 KB. lane l -> row l>>3,
    // k-granule ((l&7) ^ (row&7))  [XOR swizzle].
    const int srow  = lane >> 3;                       // 0..7 == row&7
    const int skoff = (((lane & 7) ^ srow) << 3);      // swizzled k elem-offset

    const bf16* gA = A   + (size_t)(bm + wave * 32 + srow) * 1024 + skoff;
    const bf16* gB = Bte + (size_t)(bn + wave * 32 + srow) * 1024 + skoff;
    bf16* lA = &As[wave * 2048];
    bf16* lB = &Bs[wave * 2048];

    floatx4 acc[4][4];
#pragma unroll
    for (int i = 0; i < 4; ++i)
#pragma unroll
        for (int j = 0; j < 4; ++j)
            acc[i][j] = (floatx4){0.f, 0.f, 0.f, 0.f};

    for (int k0 = 0; k0 < 1024; k0 += 64) {
        __syncthreads();
#pragma unroll
        for (int c = 0; c < 4; ++c) {
            load_lds16(gA + (size_t)c * 8192 + k0, lA + c * 512);
            load_lds16(gB + (size_t)c * 8192 + k0, lB + c * 512);
        }
        __syncthreads();   // vmcnt(0) drain before barrier

#pragma unroll
        for (int kk = 0; kk < 2; ++kk) {
            bf16x8 af[4], bfr[4];
#pragma unroll
            for (int t = 0; t < 4; ++t) {
                const int g = ((kk * 4 + quad) ^ sw) << 3;   // swizzled granule
                af[t]  = *(const bf16x8*)&As[(wm * 64 + t * 16 + l16) * 64 + g];
                bfr[t] = *(const bf16x8*)&Bs[(wn * 64 + t * 16 + l16) * 64 + g];
            }
#pragma unroll
            for (int tm = 0; tm < 4; ++tm)
#pragma unroll
                for (int tn = 0; tn < 4; ++tn)
                    acc[tm][tn] = __builtin_amdgcn_mfma_f32_16x16x32_bf16(
                        af[tm], bfr[tn], acc[tm][tn], 0, 0, 0);
        }
    }

    // epilogue. C/D layout: col = lane&15, row = quad*4 + reg (m89-verified)
    float bv[4];
#pragma unroll
    for (int tn = 0; tn < 4; ++tn)
        bv[tn] = biase[bn + wn * 64 + tn * 16 + l16];

#pragma unroll
    for (int tm = 0; tm < 4; ++tm) {
#pragma unroll
        for (int r = 0; r < 4; ++r) {
            const int gm = bm + wm * 64 + tm * 16 + quad * 4 + r;
            const size_t rowoff = (size_t)gm << 10;
            float rowmul = 1.f;
            if (emode == 1) rowmul = 1.f - auxf[gm];
#pragma unroll
            for (int tn = 0; tn < 4; ++tn) {
                const int gn = bn + wn * 64 + tn * 16 + l16;
                float val = acc[tm][tn][r] + bv[tn];
                if (emode == 0)      val = tanhf(val);
                else if (emode == 1) val = rowmul / (1.f + expf(-val));
                else if (emode == 3) val = 0.5f * val * (1.f + erff(val * 0.70710678118654752f));
                if (emode == 4) {
                    val += bf2f(auxb[rowoff + gn]);
                    Df[rowoff + gn] = val;
                } else {
                    Dbe[rowoff + gn] = f2bf(val);
                }
            }
        }
    }
}

// ---------------------------------------------------------------------------
// Chunked linear-recurrence scan: h[t] = f[t]*h[t-1] + (1-f[t])*v[t].
// T=4096 split into 64 chunks of 64. 4096 channels (b,d).
// ---------------------------------------------------------------------------
__global__ __launch_bounds__(256) void scan1_k(
    const bf16* __restrict__ v, const bf16* __restrict__ f,
    float* __restrict__ Ac, float* __restrict__ Bc)
{
    const int idx = blockIdx.x * 256 + threadIdx.x;   // 0..262143
    const int ch = idx & 4095;        // b*1024 + d
    const int c  = idx >> 12;         // chunk 0..63
    const int b  = ch >> 10, d = ch & 1023;
    const size_t base = ((size_t)(b * 4096 + c * 64) << 10) + d;
    float a = 1.f, hb = 0.f;
#pragma unroll 8
    for (int i = 0; i < 64; ++i) {
        const size_t o = base + ((size_t)i << 10);
        const float ft = bf2f(f[o]);
        const float vt = bf2f(v[o]);
        hb = fmaf(ft, hb, (1.f - ft) * vt);
        a *= ft;
    }
    Ac[c * 4096 + ch] = a;
    Bc[c * 4096 + ch] = hb;
}

__global__ __launch_bounds__(256) void scanmid_k(
    const float* __restrict__ Ac, const float* __restrict__ Bc,
    const float* __restrict__ hidden, float* __restrict__ Hin)
{
    const int ch = blockIdx.x * 256 + threadIdx.x;    // 0..4095
    float h = hidden[ch];
#pragma unroll 8
    for (int c = 0; c < 64; ++c) {
        Hin[c * 4096 + ch] = h;
        h = fmaf(Ac[c * 4096 + ch], h, Bc[c * 4096 + ch]);
    }
}

__global__ __launch_bounds__(256) void scan2_k(
    const bf16* __restrict__ v, const bf16* __restrict__ f,
    const float* __restrict__ Hin, bf16* __restrict__ hs,
    float* __restrict__ hT)
{
    const int idx = blockIdx.x * 256 + threadIdx.x;
    const int ch = idx & 4095;
    const int c  = idx >> 12;
    const int b  = ch >> 10, d = ch & 1023;
    const size_t base = ((size_t)(b * 4096 + c * 64) << 10) + d;
    float h = Hin[c * 4096 + ch];
#pragma unroll 8
    for (int i = 0; i < 64; ++i) {
        const size_t o = base + ((size_t)i << 10);
        const float ft = bf2f(f[o]);
        const float vt = bf2f(v[o]);
        h = fmaf(ft, h, (1.f - ft) * vt);
        hs[o] = f2bf(h);
    }
    if (c == 63) hT[ch] = h;
}

// ---------------------------------------------------------------------------
// LayerNorm over D=1024 (f32 in-place on d_out), one block per row.
// ---------------------------------------------------------------------------
__global__ __launch_bounds__(256) void ln_k(
    float* __restrict__ s, const float* __restrict__ g,
    const float* __restrict__ b)
{
    const int row = blockIdx.x;
    const int tid = threadIdx.x;
    const size_t off = (size_t)row << 10;
    const float4 xv = ((const float4*)(s + off))[tid];
    float sum = xv.x + xv.y + xv.z + xv.w;
    float sq  = xv.x * xv.x + xv.y * xv.y + xv.z * xv.z + xv.w * xv.w;
#pragma unroll
    for (int o = 32; o > 0; o >>= 1) {
        sum += __shfl_down(sum, o, 64);
        sq  += __shfl_down(sq,  o, 64);
    }
    __shared__ float s1[4], s2[4];
    if ((tid & 63) == 0) { s1[tid >> 6] = sum; s2[tid >> 6] = sq; }
    __syncthreads();
    sum = s1[0] + s1[1] + s1[2] + s1[3];
    sq  = s2[0] + s2[1] + s2[2] + s2[3];
    const float mean = sum * (1.f / 1024.f);
    const float var  = sq * (1.f / 1024.f) - mean * mean;
    const float rstd = rsqrtf(var + 1e-5f);
    const float4 gv = ((const float4*)g)[tid];
    const float4 bv = ((const float4*)b)[tid];
    float4 y;
    y.x = (xv.x - mean) * rstd * gv.x + bv.x;
    y.y = (xv.y - mean) * rstd * gv.y + bv.y;
    y.z = (xv.z - mean) * rstd * gv.z + bv.z;
    y.w = (xv.w - mean) * rstd * gv.w + bv.w;
    ((float4*)(s + off))[tid] = y;
}

// ---------------------------------------------------------------------------
extern "C" void kernel_launch(void* const* d_in, const int* in_sizes, int n_in,
                              void* d_out, int out_size, void* d_ws, size_t ws_size,
                              hipStream_t stream)
{
    const float* x         = (const float*)d_in[0];   // (4,4096,1024)
    const float* hidden    = (const float*)d_in[1];   // (4,1,1024)
    const float* rnn_start = (const float*)d_in[2];   // (4,4096,1)
    const float* Win       = (const float*)d_in[3];   // (2,1024,1024)
    const float* bin_      = (const float*)d_in[4];   // (2,1024)
    const float* Wout      = (const float*)d_in[5];
    const float* bout      = (const float*)d_in[6];
    const float* W1        = (const float*)d_in[7];
    const float* b1        = (const float*)d_in[8];
    const float* W2        = (const float*)d_in[9];
    const float* b2        = (const float*)d_in[10];
    const float* ln_g      = (const float*)d_in[11];
    const float* ln_b      = (const float*)d_in[12];
    float* out = (float*)d_out;                // out(16777216 f32) ++ hidden_new(4096 f32)
    float* hT  = out + (1u << 24);

    // workspace layout
    char* p = (char*)d_ws;
    bf16* Wt    = (bf16*)p;                    p += 5ull * (1u << 20) * sizeof(bf16);
    bf16* slotA = (bf16*)p;                    p += (1ull << 24) * sizeof(bf16);  // xb, later hs
    bf16* slotB = (bf16*)p;                    p += (1ull << 24) * sizeof(bf16);  // v,  later outp
    bf16* slotC = (bf16*)p;                    p += (1ull << 24) * sizeof(bf16);  // f,  later x_
    float* Ac  = (float*)p;                    p += (1ull << 18) * sizeof(float);
    float* Bc  = (float*)p;                    p += (1ull << 18) * sizeof(float);
    float* Hin = (float*)p;                    p += (1ull << 18) * sizeof(float);

    bf16* WoutT = Wt + 2u * (1u << 20);
    bf16* W1T   = Wt + 3u * (1u << 20);
    bf16* W2T   = Wt + 4u * (1u << 20);

    convx_k<<<16384, 256, 0, stream>>>((const float4*)x, slotA);
    trc_k<<<dim3(32, 32, 5), 256, 0, stream>>>(Win, Win + (1u << 20), Wout, W1, W2, Wt);

    // merged dual GEMM: y>=8 -> Win1/sigmoid.  v -> slotB, f -> slotC
    gemm_k<<<dim3(128, 16), 256, 0, stream>>>(slotA, Wt, bin_, rnn_start, nullptr,
                                              slotB, slotC, nullptr, 5);

    // chunked scan: hs -> slotA (xb dead), hT -> d_out tail
    scan1_k<<<1024, 256, 0, stream>>>(slotB, slotC, Ac, Bc);
    scanmid_k<<<16, 256, 0, stream>>>(Ac, Bc, hidden, Hin);
    scan2_k<<<1024, 256, 0, stream>>>(slotB, slotC, Hin, slotA, hT);

    // outp = hs@Wout + bout (-> slotB); x_ = gelu(outp@W1+b1) (-> slotC);
    // s = x_@W2 + b2 + outp -> f32 in d_out
    gemm_k<<<dim3(128, 8), 256, 0, stream>>>(slotA, WoutT, bout, nullptr, nullptr,
                                             slotB, nullptr, nullptr, 2);
    gemm_k<<<dim3(128, 8), 256, 0, stream>>>(slotB, W1T,   b1,   nullptr, nullptr,
                                             slotC, nullptr, nullptr, 3);
    gemm_k<<<dim3(128, 8), 256, 0, stream>>>(slotC, W2T,   b2,   nullptr, slotB,
                                             nullptr, nullptr, out, 4);

    ln_k<<<16384, 256, 0, stream>>>(out, ln_g, ln_b);
}